// Round 6
// baseline (144.770 us; speedup 1.0000x reference)
//
#include <hip/hip_runtime.h>

typedef unsigned short u16;
typedef short bf16x8 __attribute__((ext_vector_type(8)));
typedef float f32x4 __attribute__((ext_vector_type(4)));
typedef u16 u16x4 __attribute__((ext_vector_type(4)));

__device__ __forceinline__ float b2f(u16 h) {
  unsigned u = ((unsigned)h) << 16;
  return __builtin_bit_cast(float, u);
}
__device__ __forceinline__ u16 f2b(float f) {
  unsigned u = __builtin_bit_cast(unsigned, f);
  u = u + 0x7fffu + ((u >> 16) & 1u);   // round-to-nearest-even
  return (u16)(u >> 16);
}

#if defined(__has_builtin)
#if __has_builtin(__builtin_amdgcn_cvt_pk_bf16_f32)
#define HAVE_CVT_PK_BF16 1
#endif
#endif

__device__ __forceinline__ unsigned f2b_pk(float a, float b) {
#ifdef HAVE_CVT_PK_BF16
  auto v = __builtin_amdgcn_cvt_pk_bf16_f32(a, b);
  unsigned r;
  __builtin_memcpy(&r, &v, 4);
  return r;
#else
  return (unsigned)f2b(a) | (((unsigned)f2b(b)) << 16);
#endif
}
__device__ __forceinline__ bf16x8 pack8(const float* v) {
  union { unsigned u[4]; bf16x8 o; } r;
  r.u[0] = f2b_pk(v[0], v[1]);
  r.u[1] = f2b_pk(v[2], v[3]);
  r.u[2] = f2b_pk(v[4], v[5]);
  r.u[3] = f2b_pk(v[6], v[7]);
  return r.o;
}
__device__ __forceinline__ u16x4 pack4(float a, float b, float c, float d) {
  union { unsigned u[2]; u16x4 o; } r;
  r.u[0] = f2b_pk(a, b);
  r.u[1] = f2b_pk(c, d);
  return r.o;
}
__device__ __forceinline__ void gld_lds16(const void* g, void* l) {
  __builtin_amdgcn_global_load_lds(
      (__attribute__((address_space(1))) void*)(g),
      (__attribute__((address_space(3))) void*)(l), 16, 0, 0);
}

// ---------------------------------------------------------------------------
// prep: blocks [0,160): fp32 [o][c] weights -> bf16 STAGED [s8(32)][m(256)][8]
//       (layers 0,1 = post_w; 2,3,4 = pre_w)
//       blocks [160,416): x [2][256][1024] fp32 -> xt [2048][256] bf16
// ---------------------------------------------------------------------------
__global__ void dense_edge_prep(const float* __restrict__ x,
                                const float* __restrict__ pre_w,
                                const float* __restrict__ post_w,
                                u16* __restrict__ wb, u16* __restrict__ xt) {
  const int blk = blockIdx.x;
  const int t = threadIdx.x;
  if (blk < 160) {
    const int id = blk * 256 + t;
    const int layer = id >> 13;
    const int sid = id & 8191;
    const int m = sid >> 5;
    const int s8 = sid & 31;
    const float* src = (layer < 2) ? (post_w + layer * 65536)
                                   : (pre_w + (layer - 2) * 65536);
    u16* dst = wb + layer * 65536;
    f32x4 a = *(const f32x4*)(src + m * 256 + s8 * 8);
    f32x4 c = *(const f32x4*)(src + m * 256 + s8 * 8 + 4);
    float tmp[8] = {a[0], a[1], a[2], a[3], c[0], c[1], c[2], c[3]};
    *(bf16x8*)(dst + (s8 * 256 + m) * 8) = pack8(tmp);
  } else {
    __shared__ float tile[32 * 65];
    const int xb = blk - 160;
    const int b = xb >> 7;
    const int ct = (xb >> 4) & 7;
    const int ht = xb & 15;
    const int c0 = ct * 32, hw0 = ht * 64;
#pragma unroll
    for (int rep = 0; rep < 8; rep++) {
      const int idx = rep * 256 + t;
      const int cl = idx >> 6, hl = idx & 63;
      tile[cl * 65 + hl] = x[(b * 256 + c0 + cl) * 1024 + hw0 + hl];
    }
    __syncthreads();
    const int hl = t >> 2, c8 = t & 3;
    float tmp[8];
#pragma unroll
    for (int i = 0; i < 8; i++) tmp[i] = tile[(c8 * 8 + i) * 65 + hl];
    *(bf16x8*)(xt + (b * 1024 + hw0 + hl) * 256 + c0 + c8 * 8) = pack8(tmp);
  }
}

// ---------------------------------------------------------------------------
// pre: 3-layer 1x1-conv chain, block = 16 nodes, staged weights from L2.
// ---------------------------------------------------------------------------
__global__ __launch_bounds__(256, 2) void dense_edge_pre(
    const u16* __restrict__ xt, const u16* __restrict__ wpre,
    const float* __restrict__ preb, u16* __restrict__ flat) {
  __shared__ u16 feat[2][4096];
  const int t = threadIdx.x;
  const int wv = t >> 6, ln = t & 63;
  const int nb = blockIdx.x * 16;
  const int q4 = ln >> 4, r15 = ln & 15;

#pragma unroll
  for (int i = 0; i < 2; i++) {
    const int slot = wv * 128 + i * 64 + ln;
    const int s8 = slot >> 4, nl = slot & 15;
    gld_lds16(xt + (nb + nl) * 256 + s8 * 8, &feat[0][slot * 8]);
  }
  __syncthreads();

#pragma unroll
  for (int l = 0; l < 3; l++) {
    const u16* wl = wpre + l * 65536;
    f32x4 acc[4];
    f32x4 zero = {0.f, 0.f, 0.f, 0.f};
#pragma unroll
    for (int mt = 0; mt < 4; mt++) acc[mt] = zero;
#pragma unroll
    for (int s = 0; s < 8; s++) {
      bf16x8 bv = *(const bf16x8*)(&feat[l & 1][((s * 4 + q4) * 16 + r15) * 8]);
#pragma unroll
      for (int mt = 0; mt < 4; mt++) {
        bf16x8 av = *(const bf16x8*)(wl + ((s * 4 + q4) * 256 + wv * 64 + mt * 16 + r15) * 8);
        acc[mt] = __builtin_amdgcn_mfma_f32_16x16x32_bf16(av, bv, acc[mt], 0, 0, 0);
      }
    }
    if (l < 2) {
#pragma unroll
      for (int mt = 0; mt < 4; mt++) {
        const int o = wv * 64 + mt * 16 + q4 * 4;
        f32x4 bb = *(const f32x4*)(preb + l * 256 + o);
        *(u16x4*)(&feat[(l + 1) & 1][((o >> 3) * 16 + r15) * 8 + (o & 7)]) =
            pack4(fmaxf(acc[mt][0] + bb[0], 0.f), fmaxf(acc[mt][1] + bb[1], 0.f),
                  fmaxf(acc[mt][2] + bb[2], 0.f), fmaxf(acc[mt][3] + bb[3], 0.f));
      }
      __syncthreads();
    } else {
#pragma unroll
      for (int mt = 0; mt < 4; mt++) {
        const int o = wv * 64 + mt * 16 + q4 * 4;
        f32x4 bb = *(const f32x4*)(preb + 512 + o);
        *(u16x4*)(flat + (nb + r15) * 256 + o) =
            pack4(acc[mt][0] + bb[0], acc[mt][1] + bb[1],
                  acc[mt][2] + bb[2], acc[mt][3] + bb[3]);
      }
    }
  }
}

// ---------------------------------------------------------------------------
// main: 256 blocks x 512 threads (8 waves), 8 tiles/block (Nt=64).
// Producers (waves 0-3): W1 in regs, GEMM1. Consumers (4-7): W2, GEMM2+W3.
// p-row data in registers; q-rows prefetched 1 tile ahead via gld_lds with
// XOR chunk swizzle (conflict-free LDS reads, no padding).
// Step j: A: all build XX(j) from regs+qrows | prefetch q(j+1) | store(j-2)
//         B: prod GEMM1(j)->t1buf[j&1]       | cons GEMM2(j-1)+W3 partials
// ---------------------------------------------------------------------------
__global__ __launch_bounds__(512, 2) void dense_edge_main(
    const u16* __restrict__ flat, const int* __restrict__ pidx,
    const int* __restrict__ cidx, const u16* __restrict__ w1s,
    const u16* __restrict__ w2s, const float* __restrict__ b1,
    const float* __restrict__ b2, const float* __restrict__ w3,
    const float* __restrict__ b3, float* __restrict__ out) {
  __shared__ u16 xxbuf[16384];       // 32 KB [s8(32)][n(64)][8]
  __shared__ u16 t1buf[2][16384];    // 64 KB double-buffered
  __shared__ u16 qrows[2][2048];     // 2 x 4 KB: [row(8)][chunk^row (32)][8]
  __shared__ float pbuf[4][2][64];   // 2 KB

  const int t = threadIdx.x;
  const int wv = t >> 6;             // 0..7
  const int ln = t & 63;
  const int q4 = ln >> 4, r15 = ln & 15;
  const bool prod = wv < 4;
  const int cw = wv & 3;
  const int blk = blockIdx.x;        // 256
  const int tile0 = blk * 8;
  const int b = tile0 >> 10;
  const int pt = (tile0 >> 5) & 31;
  const int qt0 = tile0 & 31;
  const int p0 = pt * 8;

  // role weights in regs (staged layout, 256B coalesced rows)
  const u16* wsrc = prod ? w1s : w2s;
  bf16x8 af_w[4][8];
#pragma unroll
  for (int s = 0; s < 8; s++)
#pragma unroll
    for (int mt = 0; mt < 4; mt++)
      af_w[mt][s] = *(const bf16x8*)(wsrc + ((s * 4 + q4) * 256 + cw * 64 + mt * 16 + r15) * 8);

  // this lane's p-row chunks (pair p = ln>>3, channels wv*32..wv*32+32)
  const int pn = pidx[b * 256 + p0 + (ln >> 3)];
  bf16x8 pch[4];
#pragma unroll
  for (int i = 0; i < 4; i++)
    pch[i] = *(const bf16x8*)(flat + pn * 256 + wv * 32 + i * 8);

  // prefetch q-rows of tile 0 (producers; wave cw covers rows 2cw,2cw+1)
  if (prod) {
    const int row = 2 * cw + (ln >> 5);
    const int qn = cidx[b * 256 + qt0 * 8 + row];
    const int m = ln & 31;
    gld_lds16(flat + qn * 256 + ((m ^ (row & 7)) * 8),
              (u16*)qrows[0] + cw * 512 + ln * 8);
  }
  __syncthreads();

#pragma unroll 1
  for (int j = 0; j <= 8; j++) {
    // ---------------- phase A ----------------
    if (j < 8) {
      if (prod && j + 1 < 8) {  // prefetch q(j+1)
        const int row = 2 * cw + (ln >> 5);
        const int qn = cidx[b * 256 + (qt0 + j + 1) * 8 + row];
        const int m = ln & 31;
        gld_lds16(flat + qn * 256 + ((m ^ (row & 7)) * 8),
                  (u16*)qrows[(j + 1) & 1] + cw * 512 + ln * 8);
      }
      // build XX(j): wave wv -> slots wv*4..wv*4+4
      {
        const int q = ln & 7;
        const u16* qbase = qrows[j & 1] + q * 256;
#pragma unroll
        for (int i = 0; i < 4; i++) {
          const int c = wv * 4 + i;
          bf16x8 qv = *(const bf16x8*)(qbase + ((c ^ q) * 8));
          bf16x8 pv = pch[i];
          float d[8];
#pragma unroll
          for (int jj = 0; jj < 8; jj++) {
            float dv = b2f((u16)pv[jj]) - b2f((u16)qv[jj]);
            d[jj] = dv * dv;
          }
          *(bf16x8*)(xxbuf + (c * 64 + ln) * 8) = pack8(d);
        }
      }
    }
    if (!prod && j >= 2) {  // store out(j-2)
      const int idx = cw * 64 + ln;
      if (idx < 128) {
        const int o3 = idx >> 6;
        const int n = idx & 63;
        float v = b3[o3] + pbuf[0][o3][n] + pbuf[1][o3][n] + pbuf[2][o3][n] + pbuf[3][o3][n];
        out[((b * 2 + o3) * 256 + p0 + (n >> 3)) * 256 + (qt0 + j - 2) * 8 + (n & 7)] = v;
      }
    }
    __syncthreads();

    // ---------------- phase B ----------------
    if (prod) {
      if (j < 8) {
        f32x4 acc[4][4];
        f32x4 zero = {0.f, 0.f, 0.f, 0.f};
#pragma unroll
        for (int mt = 0; mt < 4; mt++)
#pragma unroll
          for (int nt = 0; nt < 4; nt++) acc[mt][nt] = zero;
#pragma unroll
        for (int s = 0; s < 8; s++) {
          bf16x8 bfr[4];
#pragma unroll
          for (int nt = 0; nt < 4; nt++)
            bfr[nt] = *(const bf16x8*)(xxbuf + ((s * 4 + q4) * 64 + nt * 16 + r15) * 8);
#pragma unroll
          for (int mt = 0; mt < 4; mt++)
#pragma unroll
            for (int nt = 0; nt < 4; nt++)
              acc[mt][nt] = __builtin_amdgcn_mfma_f32_16x16x32_bf16(af_w[mt][s], bfr[nt], acc[mt][nt], 0, 0, 0);
        }
        u16* tdst = t1buf[j & 1];
#pragma unroll
        for (int mt = 0; mt < 4; mt++) {
          const int o = cw * 64 + mt * 16 + q4 * 4;
          f32x4 bb = *(const f32x4*)(b1 + o);
#pragma unroll
          for (int nt = 0; nt < 4; nt++) {
            const int nn = nt * 16 + r15;
            *(u16x4*)(tdst + ((o >> 3) * 64 + nn) * 8 + (o & 7)) =
                pack4(fmaxf(acc[mt][nt][0] + bb[0], 0.f),
                      fmaxf(acc[mt][nt][1] + bb[1], 0.f),
                      fmaxf(acc[mt][nt][2] + bb[2], 0.f),
                      fmaxf(acc[mt][nt][3] + bb[3], 0.f));
          }
        }
      }
    } else if (j >= 1) {
      const u16* tsrc = t1buf[(j - 1) & 1];
      f32x4 acc[4][4];
      f32x4 zero = {0.f, 0.f, 0.f, 0.f};
#pragma unroll
      for (int mt = 0; mt < 4; mt++)
#pragma unroll
        for (int nt = 0; nt < 4; nt++) acc[mt][nt] = zero;
#pragma unroll
      for (int s = 0; s < 8; s++) {
        bf16x8 bfr[4];
#pragma unroll
        for (int nt = 0; nt < 4; nt++)
          bfr[nt] = *(const bf16x8*)(tsrc + ((s * 4 + q4) * 64 + nt * 16 + r15) * 8);
#pragma unroll
        for (int mt = 0; mt < 4; mt++)
#pragma unroll
          for (int nt = 0; nt < 4; nt++)
            acc[mt][nt] = __builtin_amdgcn_mfma_f32_16x16x32_bf16(af_w[mt][s], bfr[nt], acc[mt][nt], 0, 0, 0);
      }
      // W3 epilogue partials: relu(acc+b2) . w3
      float part[2][4] = {{0.f, 0.f, 0.f, 0.f}, {0.f, 0.f, 0.f, 0.f}};
#pragma unroll
      for (int mt = 0; mt < 4; mt++) {
        const int o = cw * 64 + mt * 16 + q4 * 4;
        f32x4 bb = *(const f32x4*)(b2 + o);
        f32x4 w3a = *(const f32x4*)(w3 + o);
        f32x4 w3b = *(const f32x4*)(w3 + 256 + o);
#pragma unroll
        for (int nt = 0; nt < 4; nt++) {
#pragma unroll
          for (int r = 0; r < 4; r++) {
            float v = fmaxf(acc[mt][nt][r] + bb[r], 0.f);
            part[0][nt] += v * w3a[r];
            part[1][nt] += v * w3b[r];
          }
        }
      }
#pragma unroll
      for (int o3 = 0; o3 < 2; o3++)
#pragma unroll
        for (int nt = 0; nt < 4; nt++) {
          part[o3][nt] += __shfl_xor(part[o3][nt], 16, 64);
          part[o3][nt] += __shfl_xor(part[o3][nt], 32, 64);
        }
      if (q4 == 0) {
#pragma unroll
        for (int o3 = 0; o3 < 2; o3++)
#pragma unroll
          for (int nt = 0; nt < 4; nt++)
            pbuf[cw][o3][nt * 16 + r15] = part[o3][nt];
      }
    }
    __syncthreads();
  }

  // final store: tile 7 (pbuf from j=8 phase B; loop-end barrier passed)
  if (!prod) {
    const int idx = cw * 64 + ln;
    if (idx < 128) {
      const int o3 = idx >> 6;
      const int n = idx & 63;
      float v = b3[o3] + pbuf[0][o3][n] + pbuf[1][o3][n] + pbuf[2][o3][n] + pbuf[3][o3][n];
      out[((b * 2 + o3) * 256 + p0 + (n >> 3)) * 256 + (qt0 + 7) * 8 + (n & 7)] = v;
    }
  }
}

// ---------------------------------------------------------------------------
extern "C" void kernel_launch(void* const* d_in, const int* in_sizes, int n_in,
                              void* d_out, int out_size, void* d_ws, size_t ws_size,
                              hipStream_t stream) {
  (void)in_sizes; (void)n_in; (void)out_size; (void)ws_size;
  const float* x          = (const float*)d_in[0];
  const int*   pidx       = (const int*)d_in[1];
  const int*   cidx       = (const int*)d_in[2];
  const float* pre_w      = (const float*)d_in[3];
  const float* pre_b      = (const float*)d_in[4];
  const float* post_w     = (const float*)d_in[5];
  const float* post_b     = (const float*)d_in[6];
  const float* post_out_w = (const float*)d_in[7];
  const float* post_out_b = (const float*)d_in[8];
  float* out = (float*)d_out;

  u16* ws   = (u16*)d_ws;
  u16* w1s  = ws;              // staged bf16 weights
  u16* w2s  = ws + 65536;
  u16* wpre = ws + 131072;
  u16* xt   = ws + 327680;     // x_t bf16 [2048][256]
  u16* flat = ws + 851968;     // node features bf16 [2048][256]

  dense_edge_prep<<<416, 256, 0, stream>>>(x, pre_w, post_w, ws, xt);
  dense_edge_pre<<<128, 256, 0, stream>>>(xt, wpre, pre_b, flat);
  dense_edge_main<<<256, 512, 0, stream>>>(flat, pidx, cidx, w1s, w2s,
                                           post_b, post_b + 256,
                                           post_out_w, post_out_b, out);
}

// Round 7
// 129.345 us; speedup vs baseline: 1.1193x; 1.1193x over previous
//
#include <hip/hip_runtime.h>

typedef unsigned short u16;
typedef short bf16x8 __attribute__((ext_vector_type(8)));
typedef float f32x4 __attribute__((ext_vector_type(4)));
typedef u16 u16x4 __attribute__((ext_vector_type(4)));

__device__ __forceinline__ float b2f(u16 h) {
  unsigned u = ((unsigned)h) << 16;
  return __builtin_bit_cast(float, u);
}
__device__ __forceinline__ u16 f2b(float f) {
  unsigned u = __builtin_bit_cast(unsigned, f);
  u = u + 0x7fffu + ((u >> 16) & 1u);   // round-to-nearest-even
  return (u16)(u >> 16);
}

#if defined(__has_builtin)
#if __has_builtin(__builtin_amdgcn_cvt_pk_bf16_f32)
#define HAVE_CVT_PK_BF16 1
#endif
#endif

__device__ __forceinline__ unsigned f2b_pk(float a, float b) {
#ifdef HAVE_CVT_PK_BF16
  auto v = __builtin_amdgcn_cvt_pk_bf16_f32(a, b);
  unsigned r;
  __builtin_memcpy(&r, &v, 4);
  return r;
#else
  return (unsigned)f2b(a) | (((unsigned)f2b(b)) << 16);
#endif
}
__device__ __forceinline__ bf16x8 pack8(const float* v) {
  union { unsigned u[4]; bf16x8 o; } r;
  r.u[0] = f2b_pk(v[0], v[1]);
  r.u[1] = f2b_pk(v[2], v[3]);
  r.u[2] = f2b_pk(v[4], v[5]);
  r.u[3] = f2b_pk(v[6], v[7]);
  return r.o;
}
__device__ __forceinline__ u16x4 pack4(float a, float b, float c, float d) {
  union { unsigned u[2]; u16x4 o; } r;
  r.u[0] = f2b_pk(a, b);
  r.u[1] = f2b_pk(c, d);
  return r.o;
}
__device__ __forceinline__ void gld_lds16(const void* g, void* l) {
  __builtin_amdgcn_global_load_lds(
      (__attribute__((address_space(1))) void*)(g),
      (__attribute__((address_space(3))) void*)(l), 16, 0, 0);
}

// ---------------------------------------------------------------------------
// prep: blocks [0,160): fp32 [o][c] weights -> bf16 STAGED [s8(32)][m(256)][8]
//       (layers 0,1 = post_w; 2,3,4 = pre_w)
//       blocks [160,416): x [2][256][1024] fp32 -> xt [2048][256] bf16
// ---------------------------------------------------------------------------
__global__ void dense_edge_prep(const float* __restrict__ x,
                                const float* __restrict__ pre_w,
                                const float* __restrict__ post_w,
                                u16* __restrict__ wb, u16* __restrict__ xt) {
  const int blk = blockIdx.x;
  const int t = threadIdx.x;
  if (blk < 160) {
    const int id = blk * 256 + t;
    const int layer = id >> 13;
    const int sid = id & 8191;
    const int m = sid >> 5;
    const int s8 = sid & 31;
    const float* src = (layer < 2) ? (post_w + layer * 65536)
                                   : (pre_w + (layer - 2) * 65536);
    u16* dst = wb + layer * 65536;
    f32x4 a = *(const f32x4*)(src + m * 256 + s8 * 8);
    f32x4 c = *(const f32x4*)(src + m * 256 + s8 * 8 + 4);
    float tmp[8] = {a[0], a[1], a[2], a[3], c[0], c[1], c[2], c[3]};
    *(bf16x8*)(dst + (s8 * 256 + m) * 8) = pack8(tmp);
  } else {
    __shared__ float tile[32 * 65];
    const int xb = blk - 160;
    const int b = xb >> 7;
    const int ct = (xb >> 4) & 7;
    const int ht = xb & 15;
    const int c0 = ct * 32, hw0 = ht * 64;
#pragma unroll
    for (int rep = 0; rep < 8; rep++) {
      const int idx = rep * 256 + t;
      const int cl = idx >> 6, hl = idx & 63;
      tile[cl * 65 + hl] = x[(b * 256 + c0 + cl) * 1024 + hw0 + hl];
    }
    __syncthreads();
    const int hl = t >> 2, c8 = t & 3;
    float tmp[8];
#pragma unroll
    for (int i = 0; i < 8; i++) tmp[i] = tile[(c8 * 8 + i) * 65 + hl];
    *(bf16x8*)(xt + (b * 1024 + hw0 + hl) * 256 + c0 + c8 * 8) = pack8(tmp);
  }
}

// ---------------------------------------------------------------------------
// pre: 3-layer 1x1-conv chain, block = 16 nodes, staged weights from L2.
// ---------------------------------------------------------------------------
__global__ __launch_bounds__(256, 2) void dense_edge_pre(
    const u16* __restrict__ xt, const u16* __restrict__ wpre,
    const float* __restrict__ preb, u16* __restrict__ flat) {
  __shared__ u16 feat[2][4096];
  const int t = threadIdx.x;
  const int wv = t >> 6, ln = t & 63;
  const int nb = blockIdx.x * 16;
  const int q4 = ln >> 4, r15 = ln & 15;

#pragma unroll
  for (int i = 0; i < 2; i++) {
    const int slot = wv * 128 + i * 64 + ln;
    const int s8 = slot >> 4, nl = slot & 15;
    gld_lds16(xt + (nb + nl) * 256 + s8 * 8, &feat[0][slot * 8]);
  }
  __syncthreads();

#pragma unroll
  for (int l = 0; l < 3; l++) {
    const u16* wl = wpre + l * 65536;
    f32x4 acc[4];
    f32x4 zero = {0.f, 0.f, 0.f, 0.f};
#pragma unroll
    for (int mt = 0; mt < 4; mt++) acc[mt] = zero;
#pragma unroll
    for (int s = 0; s < 8; s++) {
      bf16x8 bv = *(const bf16x8*)(&feat[l & 1][((s * 4 + q4) * 16 + r15) * 8]);
#pragma unroll
      for (int mt = 0; mt < 4; mt++) {
        bf16x8 av = *(const bf16x8*)(wl + ((s * 4 + q4) * 256 + wv * 64 + mt * 16 + r15) * 8);
        acc[mt] = __builtin_amdgcn_mfma_f32_16x16x32_bf16(av, bv, acc[mt], 0, 0, 0);
      }
    }
    if (l < 2) {
#pragma unroll
      for (int mt = 0; mt < 4; mt++) {
        const int o = wv * 64 + mt * 16 + q4 * 4;
        f32x4 bb = *(const f32x4*)(preb + l * 256 + o);
        *(u16x4*)(&feat[(l + 1) & 1][((o >> 3) * 16 + r15) * 8 + (o & 7)]) =
            pack4(fmaxf(acc[mt][0] + bb[0], 0.f), fmaxf(acc[mt][1] + bb[1], 0.f),
                  fmaxf(acc[mt][2] + bb[2], 0.f), fmaxf(acc[mt][3] + bb[3], 0.f));
      }
      __syncthreads();
    } else {
#pragma unroll
      for (int mt = 0; mt < 4; mt++) {
        const int o = wv * 64 + mt * 16 + q4 * 4;
        f32x4 bb = *(const f32x4*)(preb + 512 + o);
        *(u16x4*)(flat + (nb + r15) * 256 + o) =
            pack4(acc[mt][0] + bb[0], acc[mt][1] + bb[1],
                  acc[mt][2] + bb[2], acc[mt][3] + bb[3]);
      }
    }
  }
}

// ---------------------------------------------------------------------------
// main: 2048 blocks x 256 threads (4 waves), 1 tile (8p x 8q, Nt=64) each.
// No wave specialization. Per block:
//   build XX (4-way c-split) -> GEMM1 (W1 frags in regs from staged L2)
//   -> relu+b1 -> t1buf -> reload regs with W2 -> GEMM2 -> W3 reg epilogue.
// LDS 66 KB -> 2 independent blocks/CU hide each other's latency/barriers.
// VGPR ~230/lane (af_w 128 + acc 64) -> 2 waves/SIMD, launch_bounds(256,2).
// ---------------------------------------------------------------------------
__global__ __launch_bounds__(256, 2) void dense_edge_main(
    const u16* __restrict__ flat, const int* __restrict__ pidx,
    const int* __restrict__ cidx, const u16* __restrict__ w1s,
    const u16* __restrict__ w2s, const float* __restrict__ b1,
    const float* __restrict__ b2, const float* __restrict__ w3,
    const float* __restrict__ b3, float* __restrict__ out) {
  __shared__ u16 xxbuf[16384];       // 32 KB [s8(32)][n(64)][8]
  __shared__ u16 t1buf[16384];       // 32 KB same layout
  __shared__ float pbuf[4][2][64];   // 2 KB

  const int t = threadIdx.x;
  const int wv = t >> 6;
  const int ln = t & 63;
  const int q4 = ln >> 4, r15 = ln & 15;
  const int blk = blockIdx.x;        // 2048: b(1) pt(5) qt(5)
  const int b = blk >> 10;
  const int pt = (blk >> 5) & 31;
  const int qt = blk & 31;
  const int p0 = pt * 8, q0 = qt * 8;

  // W1 fragments into regs FIRST (independent loads -> overlap gather latency)
  bf16x8 af_w[4][8];
#pragma unroll
  for (int s = 0; s < 8; s++)
#pragma unroll
    for (int mt = 0; mt < 4; mt++)
      af_w[mt][s] = *(const bf16x8*)(w1s + ((s * 4 + q4) * 256 + wv * 64 + mt * 16 + r15) * 8);

  // build XX: lane = pair n = ln, c-block = wv (64 channels = 8 slots)
  {
    const int pn = pidx[b * 256 + p0 + (ln >> 3)];
    const int qn = cidx[b * 256 + q0 + (ln & 7)];
    const u16* prow = flat + pn * 256 + wv * 64;
    const u16* qrow = flat + qn * 256 + wv * 64;
#pragma unroll
    for (int i = 0; i < 8; i++) {
      bf16x8 av = *(const bf16x8*)(prow + i * 8);
      bf16x8 bv = *(const bf16x8*)(qrow + i * 8);
      float d[8];
#pragma unroll
      for (int jj = 0; jj < 8; jj++) {
        float dv = b2f((u16)av[jj]) - b2f((u16)bv[jj]);
        d[jj] = dv * dv;
      }
      *(bf16x8*)(xxbuf + ((wv * 8 + i) * 64 + ln) * 8) = pack8(d);
    }
  }
  __syncthreads();   // XX visible

  // ---- GEMM1 ----
  f32x4 acc[4][4];
  {
    f32x4 zero = {0.f, 0.f, 0.f, 0.f};
#pragma unroll
    for (int mt = 0; mt < 4; mt++)
#pragma unroll
      for (int nt = 0; nt < 4; nt++) acc[mt][nt] = zero;
  }
#pragma unroll
  for (int s = 0; s < 8; s++) {
    bf16x8 bfr[4];
#pragma unroll
    for (int nt = 0; nt < 4; nt++)
      bfr[nt] = *(const bf16x8*)(xxbuf + ((s * 4 + q4) * 64 + nt * 16 + r15) * 8);
#pragma unroll
    for (int mt = 0; mt < 4; mt++)
#pragma unroll
      for (int nt = 0; nt < 4; nt++)
        acc[mt][nt] = __builtin_amdgcn_mfma_f32_16x16x32_bf16(af_w[mt][s], bfr[nt], acc[mt][nt], 0, 0, 0);
  }

  // T1 writeback (relu + b1); then reload af_w with W2 (last use of W1 above)
#pragma unroll
  for (int mt = 0; mt < 4; mt++) {
    const int o = wv * 64 + mt * 16 + q4 * 4;
    f32x4 bb = *(const f32x4*)(b1 + o);
#pragma unroll
    for (int nt = 0; nt < 4; nt++) {
      const int nn = nt * 16 + r15;
      *(u16x4*)(t1buf + ((o >> 3) * 64 + nn) * 8 + (o & 7)) =
          pack4(fmaxf(acc[mt][nt][0] + bb[0], 0.f),
                fmaxf(acc[mt][nt][1] + bb[1], 0.f),
                fmaxf(acc[mt][nt][2] + bb[2], 0.f),
                fmaxf(acc[mt][nt][3] + bb[3], 0.f));
      acc[mt][nt][0] = 0.f; acc[mt][nt][1] = 0.f;
      acc[mt][nt][2] = 0.f; acc[mt][nt][3] = 0.f;
    }
  }
#pragma unroll
  for (int s = 0; s < 8; s++)
#pragma unroll
    for (int mt = 0; mt < 4; mt++)
      af_w[mt][s] = *(const bf16x8*)(w2s + ((s * 4 + q4) * 256 + wv * 64 + mt * 16 + r15) * 8);
  __syncthreads();   // T1 visible

  // ---- GEMM2 ----
#pragma unroll
  for (int s = 0; s < 8; s++) {
    bf16x8 bfr[4];
#pragma unroll
    for (int nt = 0; nt < 4; nt++)
      bfr[nt] = *(const bf16x8*)(t1buf + ((s * 4 + q4) * 64 + nt * 16 + r15) * 8);
#pragma unroll
    for (int mt = 0; mt < 4; mt++)
#pragma unroll
      for (int nt = 0; nt < 4; nt++)
        acc[mt][nt] = __builtin_amdgcn_mfma_f32_16x16x32_bf16(af_w[mt][s], bfr[nt], acc[mt][nt], 0, 0, 0);
  }

  // W3 register epilogue: part[o3][nt] over this wave's 64 rows
  {
    float part[2][4] = {{0.f, 0.f, 0.f, 0.f}, {0.f, 0.f, 0.f, 0.f}};
#pragma unroll
    for (int mt = 0; mt < 4; mt++) {
      const int o = wv * 64 + mt * 16 + q4 * 4;
      f32x4 bb = *(const f32x4*)(b2 + o);
      f32x4 w3a = *(const f32x4*)(w3 + o);
      f32x4 w3b = *(const f32x4*)(w3 + 256 + o);
#pragma unroll
      for (int nt = 0; nt < 4; nt++) {
#pragma unroll
        for (int r = 0; r < 4; r++) {
          float v = fmaxf(acc[mt][nt][r] + bb[r], 0.f);
          part[0][nt] += v * w3a[r];
          part[1][nt] += v * w3b[r];
        }
      }
    }
#pragma unroll
    for (int o3 = 0; o3 < 2; o3++)
#pragma unroll
      for (int nt = 0; nt < 4; nt++) {
        part[o3][nt] += __shfl_xor(part[o3][nt], 16, 64);
        part[o3][nt] += __shfl_xor(part[o3][nt], 32, 64);
      }
    if (q4 == 0) {
#pragma unroll
      for (int o3 = 0; o3 < 2; o3++)
#pragma unroll
        for (int nt = 0; nt < 4; nt++)
          pbuf[wv][o3][nt * 16 + r15] = part[o3][nt];
    }
  }
  __syncthreads();   // partials visible

  if (t < 128) {
    const int o3 = t >> 6;
    const int n = t & 63;
    float v = b3[o3] + pbuf[0][o3][n] + pbuf[1][o3][n] + pbuf[2][o3][n] + pbuf[3][o3][n];
    out[((b * 2 + o3) * 256 + p0 + (n >> 3)) * 256 + q0 + (n & 7)] = v;
  }
}

// ---------------------------------------------------------------------------
extern "C" void kernel_launch(void* const* d_in, const int* in_sizes, int n_in,
                              void* d_out, int out_size, void* d_ws, size_t ws_size,
                              hipStream_t stream) {
  (void)in_sizes; (void)n_in; (void)out_size; (void)ws_size;
  const float* x          = (const float*)d_in[0];
  const int*   pidx       = (const int*)d_in[1];
  const int*   cidx       = (const int*)d_in[2];
  const float* pre_w      = (const float*)d_in[3];
  const float* pre_b      = (const float*)d_in[4];
  const float* post_w     = (const float*)d_in[5];
  const float* post_b     = (const float*)d_in[6];
  const float* post_out_w = (const float*)d_in[7];
  const float* post_out_b = (const float*)d_in[8];
  float* out = (float*)d_out;

  u16* ws   = (u16*)d_ws;
  u16* w1s  = ws;              // staged bf16 weights
  u16* w2s  = ws + 65536;
  u16* wpre = ws + 131072;
  u16* xt   = ws + 327680;     // x_t bf16 [2048][256]
  u16* flat = ws + 851968;     // node features bf16 [2048][256]

  dense_edge_prep<<<416, 256, 0, stream>>>(x, pre_w, post_w, ws, xt);
  dense_edge_pre<<<128, 256, 0, stream>>>(xt, wpre, pre_b, flat);
  dense_edge_main<<<2048, 256, 0, stream>>>(flat, pidx, cidx, w1s, w2s,
                                            post_b, post_b + 256,
                                            post_out_w, post_out_b, out);
}